// Round 5
// baseline (60.955 us; speedup 1.0000x reference)
//
#include <hip/hip_runtime.h>

// Separable QP projection via bisection on lambda.
// ONE WAVE PER ROW (64 threads), 64 elements/lane held in registers
// (za/ia/ma/Ma[64] ~ 256 VGPRs; launch_bounds(64,1) allows up to 512).
// Zero LDS, zero barriers: per iteration 192 independent VALU ops
// (fma/med3/add, 8 interleaved accumulator chains) + 6-step DPP wave
// reduce + readlane broadcast + uniform lo/hi update.
//
// R4 post-mortem: block-wide reduce/barrier overhead was ~free (TLP
// hides it); the cost is eval issue efficiency under block lockstep.
// This removes all block machinery.
//
// ITERS=12: width 18/2^12 = 4.4e-3 -> lam err 2.2e-3 -> x err ~1.1e-3,
// plus measured ~4e-3 fp32 branch-flip noise floor << 2e-2 threshold.

#define BISECT_ITERS 12

// ---- DPP wave64 reduction helpers (gfx9-family row ops) ----
template<int CTRL, int RM>
__device__ __forceinline__ float dpp_add(float v) {
    int t = __builtin_amdgcn_update_dpp(0, __float_as_int(v), CTRL, RM, 0xf, false);
    return v + __int_as_float(t);
}
template<int CTRL, int RM>
__device__ __forceinline__ float dpp_min(float v) {
    int t = __builtin_amdgcn_update_dpp(0x7f800000, __float_as_int(v), CTRL, RM, 0xf, false);
    return fminf(v, __int_as_float(t));
}
template<int CTRL, int RM>
__device__ __forceinline__ float dpp_max(float v) {
    int t = __builtin_amdgcn_update_dpp(0xff800000, __float_as_int(v), CTRL, RM, 0xf, false);
    return fmaxf(v, __int_as_float(t));
}

__device__ __forceinline__ float wave_sum(float v) {
    v = dpp_add<0x111, 0xf>(v);   // row_shr:1
    v = dpp_add<0x112, 0xf>(v);   // row_shr:2
    v = dpp_add<0x114, 0xf>(v);   // row_shr:4
    v = dpp_add<0x118, 0xf>(v);   // row_shr:8
    v = dpp_add<0x142, 0xa>(v);   // row_bcast:15
    v = dpp_add<0x143, 0xc>(v);   // row_bcast:31
    return __int_as_float(__builtin_amdgcn_readlane(__float_as_int(v), 63));
}
__device__ __forceinline__ float wave_min(float v) {
    v = dpp_min<0x111, 0xf>(v);
    v = dpp_min<0x112, 0xf>(v);
    v = dpp_min<0x114, 0xf>(v);
    v = dpp_min<0x118, 0xf>(v);
    v = dpp_min<0x142, 0xa>(v);
    v = dpp_min<0x143, 0xc>(v);
    return __int_as_float(__builtin_amdgcn_readlane(__float_as_int(v), 63));
}
__device__ __forceinline__ float wave_max(float v) {
    v = dpp_max<0x111, 0xf>(v);
    v = dpp_max<0x112, 0xf>(v);
    v = dpp_max<0x114, 0xf>(v);
    v = dpp_max<0x118, 0xf>(v);
    v = dpp_max<0x142, 0xa>(v);
    v = dpp_max<0x143, 0xc>(v);
    return __int_as_float(__builtin_amdgcn_readlane(__float_as_int(v), 63));
}

__global__ __launch_bounds__(64, 1) void qp_proj_wave_n4096(
    const float* __restrict__ z,
    const float* __restrict__ gamma,
    const float* __restrict__ mlo,
    const float* __restrict__ mhi,
    const float* __restrict__ xi,
    float* __restrict__ out)
{
    constexpr int N = 4096;
    const int row  = blockIdx.x;
    const int lane = threadIdx.x;     // 0..63 (one wave)

    const float4* zrow = reinterpret_cast<const float4*>(z + (size_t)row * N);
    const float4* g4   = reinterpret_cast<const float4*>(gamma);
    const float4* m4   = reinterpret_cast<const float4*>(mlo);
    const float4* M4   = reinterpret_cast<const float4*>(mhi);
    float4*       orow = reinterpret_cast<float4*>(out + (size_t)row * N);

    // Per-lane element state: 64 elems -> fully unrolled, static indices.
    float za[64], ia[64], ma[64], Ma[64];

    float pmin0 =  INFINITY, pmin1 =  INFINITY, pmin2 =  INFINITY, pmin3 =  INFINITY;
    float pmax0 = -INFINITY, pmax1 = -INFINITY, pmax2 = -INFINITY, pmax3 = -INFINITY;

    #pragma unroll
    for (int k = 0; k < 16; ++k) {
        const int idx = lane + k * 64;           // float4 index, 1KB/instr coalesced
        const float4 zz = zrow[idx];
        const float4 gg = g4[idx];
        const float4 mm = m4[idx];
        const float4 MM = M4[idx];

        const float zs[4] = {zz.x, zz.y, zz.z, zz.w};
        const float gs[4] = {gg.x, gg.y, gg.z, gg.w};
        const float ms[4] = {mm.x, mm.y, mm.z, mm.w};
        const float Ms[4] = {MM.x, MM.y, MM.z, MM.w};

        #pragma unroll
        for (int c = 0; c < 4; ++c) {
            const int j = 4 * k + c;
            const float tg = 2.0f * gs[c];
            za[j] = zs[c];
            ia[j] = 1.0f / tg;
            ma[j] = ms[c];
            Ma[j] = Ms[c];
            const float vlo = tg * (ms[c] - zs[c]);
            const float vhi = tg * (Ms[c] - zs[c]);
            if (c == 0) { pmin0 = fminf(pmin0, vlo); pmax0 = fmaxf(pmax0, vhi); }
            if (c == 1) { pmin1 = fminf(pmin1, vlo); pmax1 = fmaxf(pmax1, vhi); }
            if (c == 2) { pmin2 = fminf(pmin2, vlo); pmax2 = fmaxf(pmax2, vhi); }
            if (c == 3) { pmin3 = fminf(pmin3, vlo); pmax3 = fmaxf(pmax3, vhi); }
        }
    }

    float lo = wave_min(fminf(fminf(pmin0, pmin1), fminf(pmin2, pmin3)));
    float hi = wave_max(fmaxf(fmaxf(pmax0, pmax1), fmaxf(pmax2, pmax3)));

    const float xir = xi[row];

    // ---- bisection: no LDS, no barriers ----
    for (int it = 0; it < BISECT_ITERS; ++it) {
        const float mid = 0.5f * (lo + hi);
        float t[8] = {0.f, 0.f, 0.f, 0.f, 0.f, 0.f, 0.f, 0.f};
        #pragma unroll
        for (int j = 0; j < 64; ++j) {
            const float x = fmaf(mid, ia[j], za[j]);
            t[j & 7] += __builtin_amdgcn_fmed3f(x, ma[j], Ma[j]);
        }
        #pragma unroll
        for (int w = 4; w > 0; w >>= 1)
            #pragma unroll
            for (int j = 0; j < w; ++j)
                t[j] += t[j + w];
        const float s = wave_sum(t[0]);
        const float gmid = s - xir;
        if (gmid > 0.0f) hi = mid; else lo = mid;
    }

    const float lam = 0.5f * (lo + hi);

    // ---- final x ----
    #pragma unroll
    for (int k = 0; k < 16; ++k) {
        const int idx = lane + k * 64;
        float4 r;
        float xs[4];
        #pragma unroll
        for (int c = 0; c < 4; ++c) {
            const int j = 4 * k + c;
            const float x = fmaf(lam, ia[j], za[j]);
            xs[c] = __builtin_amdgcn_fmed3f(x, ma[j], Ma[j]);
        }
        r.x = xs[0]; r.y = xs[1]; r.z = xs[2]; r.w = xs[3];
        orow[idx] = r;
    }
}

extern "C" void kernel_launch(void* const* d_in, const int* in_sizes, int n_in,
                              void* d_out, int out_size, void* d_ws, size_t ws_size,
                              hipStream_t stream) {
    const float* z     = (const float*)d_in[0];
    const float* gamma = (const float*)d_in[1];
    const float* m     = (const float*)d_in[2];
    const float* M     = (const float*)d_in[3];
    const float* xi    = (const float*)d_in[4];
    float* out = (float*)d_out;

    const int B = in_sizes[4];   // rows (xi has one entry per row)
    // One wave per row; kernel specialized to N == 4096 (64 elems/lane).
    qp_proj_wave_n4096<<<dim3(B), dim3(64), 0, stream>>>(z, gamma, m, M, xi, out);
}

// Round 6
// 34.035 us; speedup vs baseline: 1.7909x; 1.7909x over previous
//
#include <hip/hip_runtime.h>

// Separable QP projection: hybrid bisection + Illinois false-position on
// lambda. One 256-thread block per row (B=4096, N=4096), 16 elems/thread
// in registers (R3 structure: best measured, 36us @ 12 sums).
//
// Cost model (R1-R5): dur ~= F + nsums*1.7us. This round cuts nsums 12->9:
// 6 bisections (localize through the high-slope region, width 18/64~0.28)
// + 3 Illinois false-position steps + final interpolated lambda. g is
// monotone piecewise-linear; with only ~1-3 breakpoints left in the
// bracket, false position converges ~exactly -> absmax should DROP below
// the 3.9e-3 bisection-12 noise floor.
//
// Endpoint g values are free: g(lo)=sum(m)-xi, g(hi)=sum(M)-xi, reduced
// once in the prologue sharing the existing barrier.

#define BISECT_STEPS 6
#define TOTAL_STEPS  9   // 6 bisection + 3 Illinois

// ---- DPP wave64 reduction helpers (gfx9-family row ops) ----
template<int CTRL, int RM>
__device__ __forceinline__ float dpp_add(float v) {
    int t = __builtin_amdgcn_update_dpp(0, __float_as_int(v), CTRL, RM, 0xf, false);
    return v + __int_as_float(t);
}
template<int CTRL, int RM>
__device__ __forceinline__ float dpp_min(float v) {
    int t = __builtin_amdgcn_update_dpp(0x7f800000, __float_as_int(v), CTRL, RM, 0xf, false);
    return fminf(v, __int_as_float(t));
}
template<int CTRL, int RM>
__device__ __forceinline__ float dpp_max(float v) {
    int t = __builtin_amdgcn_update_dpp(0xff800000, __float_as_int(v), CTRL, RM, 0xf, false);
    return fmaxf(v, __int_as_float(t));
}

__device__ __forceinline__ float wave_sum(float v) {
    v = dpp_add<0x111, 0xf>(v);   // row_shr:1
    v = dpp_add<0x112, 0xf>(v);   // row_shr:2
    v = dpp_add<0x114, 0xf>(v);   // row_shr:4
    v = dpp_add<0x118, 0xf>(v);   // row_shr:8
    v = dpp_add<0x142, 0xa>(v);   // row_bcast:15
    v = dpp_add<0x143, 0xc>(v);   // row_bcast:31
    return __int_as_float(__builtin_amdgcn_readlane(__float_as_int(v), 63));
}
__device__ __forceinline__ float wave_min(float v) {
    v = dpp_min<0x111, 0xf>(v);
    v = dpp_min<0x112, 0xf>(v);
    v = dpp_min<0x114, 0xf>(v);
    v = dpp_min<0x118, 0xf>(v);
    v = dpp_min<0x142, 0xa>(v);
    v = dpp_min<0x143, 0xc>(v);
    return __int_as_float(__builtin_amdgcn_readlane(__float_as_int(v), 63));
}
__device__ __forceinline__ float wave_max(float v) {
    v = dpp_max<0x111, 0xf>(v);
    v = dpp_max<0x112, 0xf>(v);
    v = dpp_max<0x114, 0xf>(v);
    v = dpp_max<0x118, 0xf>(v);
    v = dpp_max<0x142, 0xa>(v);
    v = dpp_max<0x143, 0xc>(v);
    return __int_as_float(__builtin_amdgcn_readlane(__float_as_int(v), 63));
}

__global__ __launch_bounds__(256) void qp_proj_n4096(
    const float* __restrict__ z,
    const float* __restrict__ gamma,
    const float* __restrict__ mlo,
    const float* __restrict__ mhi,
    const float* __restrict__ xi,
    float* __restrict__ out)
{
    constexpr int N = 4096;
    const int row  = blockIdx.x;
    const int tid  = threadIdx.x;     // 0..255
    const int lane = tid & 63;
    const int wid  = tid >> 6;        // 0..3

    const float4* zrow = reinterpret_cast<const float4*>(z + (size_t)row * N);
    const float4* g4   = reinterpret_cast<const float4*>(gamma);
    const float4* m4   = reinterpret_cast<const float4*>(mlo);
    const float4* M4   = reinterpret_cast<const float4*>(mhi);
    float4*       orow = reinterpret_cast<float4*>(out + (size_t)row * N);

    // Per-thread element state (static indices after full unroll -> registers).
    float za[16], ia[16], ma[16], Ma[16];

    float pmin =  INFINITY;   // partial min of 2g*(m - z)
    float pmax = -INFINITY;   // partial max of 2g*(M - z)
    float psm  = 0.0f;        // partial sum of m  (for g(lo) = sum m - xi)
    float psM  = 0.0f;        // partial sum of M  (for g(hi) = sum M - xi)

    #pragma unroll
    for (int k = 0; k < 4; ++k) {
        const int idx = tid + k * 256;           // float4 index, coalesced
        const float4 zz = zrow[idx];
        const float4 gg = g4[idx];
        const float4 mm = m4[idx];
        const float4 MM = M4[idx];

        const float zs[4] = {zz.x, zz.y, zz.z, zz.w};
        const float gs[4] = {gg.x, gg.y, gg.z, gg.w};
        const float ms[4] = {mm.x, mm.y, mm.z, mm.w};
        const float Ms[4] = {MM.x, MM.y, MM.z, MM.w};

        #pragma unroll
        for (int c = 0; c < 4; ++c) {
            const int j = 4 * k + c;
            const float tg = 2.0f * gs[c];
            za[j] = zs[c];
            ia[j] = 1.0f / tg;
            ma[j] = ms[c];
            Ma[j] = Ms[c];
            pmin = fminf(pmin, tg * (ms[c] - zs[c]));
            pmax = fmaxf(pmax, tg * (Ms[c] - zs[c]));
            psm += ms[c];
            psM += Ms[c];
        }
    }

    // ---- block reduce: bounds + endpoint g values (one barrier) ----
    __shared__ float wmin[4], wmax[4], wsm[4], wsM[4];
    __shared__ float wsum[2][4];      // double-buffered: one barrier per iter

    pmin = wave_min(pmin);
    pmax = wave_max(pmax);
    psm  = wave_sum(psm);
    psM  = wave_sum(psM);
    if (lane == 0) { wmin[wid] = pmin; wmax[wid] = pmax; wsm[wid] = psm; wsM[wid] = psM; }
    __syncthreads();
    float lo = fminf(fminf(wmin[0], wmin[1]), fminf(wmin[2], wmin[3]));
    float hi = fmaxf(fmaxf(wmax[0], wmax[1]), fmaxf(wmax[2], wmax[3]));

    const float xir = xi[row];
    float glo = (wsm[0] + wsm[1] + wsm[2] + wsm[3]) - xir;   // <= 0 at lo
    float ghi = (wsM[0] + wsM[1] + wsM[2] + wsM[3]) - xir;   // >= 0 at hi
    int side = 0;

    // ---- 6 bisection + 3 Illinois steps, each ONE sum ----
    for (int it = 0; it < TOTAL_STEPS; ++it) {
        const float w = hi - lo;
        float cand;
        if (it < BISECT_STEPS) {
            cand = fmaf(0.5f, w, lo);
        } else {
            const float denom = ghi - glo;           // > 0 (bracket invariant)
            cand = (lo * ghi - hi * glo) / denom;    // false-position point
            // keep strictly interior so bracket always shrinks
            cand = fminf(fmaxf(cand, fmaf(0.0625f, w, lo)),
                         fmaf(-0.0625f, w, hi));
        }

        float t[16];
        #pragma unroll
        for (int j = 0; j < 16; ++j) {
            const float x = fmaf(cand, ia[j], za[j]);
            t[j] = __builtin_amdgcn_fmed3f(x, ma[j], Ma[j]);
        }
        #pragma unroll
        for (int wd = 8; wd > 0; wd >>= 1)
            #pragma unroll
            for (int j = 0; j < wd; ++j)
                t[j] += t[j + wd];
        const float sw = wave_sum(t[0]);

        const int p = it & 1;
        if (lane == 0) wsum[p][wid] = sw;
        __syncthreads();
        // write to wsum[p] at iter it is protected from iter it-2's reads
        // by the barrier at iter it-1 -> single barrier suffices.
        const float s = (wsum[p][0] + wsum[p][1] + wsum[p][2] + wsum[p][3]) - xir;

        if (s > 0.0f) {                 // root below cand (reference semantics)
            hi = cand;
            if (side == 1) glo *= 0.5f; // Illinois: stale-endpoint halving
            ghi = s;
            side = 1;
        } else {
            lo = cand;
            if (side == -1) ghi *= 0.5f;
            glo = s;
            side = -1;
        }
    }

    // final lambda: interpolated root of the last bracket (piecewise-linear
    // g -> near-exact), clamped into [lo,hi]; midpoint fallback if degenerate.
    const float denom = ghi - glo;
    float lam = (denom > 0.0f) ? (lo * ghi - hi * glo) / denom
                               : fmaf(0.5f, hi - lo, lo);
    lam = fminf(fmaxf(lam, lo), hi);

    // ---- final x ----
    #pragma unroll
    for (int k = 0; k < 4; ++k) {
        const int idx = tid + k * 256;
        float4 r;
        float xs[4];
        #pragma unroll
        for (int c = 0; c < 4; ++c) {
            const int j = 4 * k + c;
            const float x = fmaf(lam, ia[j], za[j]);
            xs[c] = __builtin_amdgcn_fmed3f(x, ma[j], Ma[j]);
        }
        r.x = xs[0]; r.y = xs[1]; r.z = xs[2]; r.w = xs[3];
        orow[idx] = r;
    }
}

extern "C" void kernel_launch(void* const* d_in, const int* in_sizes, int n_in,
                              void* d_out, int out_size, void* d_ws, size_t ws_size,
                              hipStream_t stream) {
    const float* z     = (const float*)d_in[0];
    const float* gamma = (const float*)d_in[1];
    const float* m     = (const float*)d_in[2];
    const float* M     = (const float*)d_in[3];
    const float* xi    = (const float*)d_in[4];
    float* out = (float*)d_out;

    const int B = in_sizes[4];   // rows (xi has one entry per row)
    // Kernel is specialized to N == 4096 (16 elements / thread, 256 threads).
    qp_proj_n4096<<<dim3(B), dim3(256), 0, stream>>>(z, gamma, m, M, xi, out);
}